// Round 16
// baseline (30.750 us; speedup 1.0000x reference)
//
#include <hip/hip_runtime.h>
#include <hip/hip_bf16.h>
#include <cstdint>

#define DIM 128
#define PS 33            // part[] row stride (32+1 pad)

__device__ __forceinline__ float prelu(float x, float a) {
    return x >= 0.f ? x : a * x;
}

// ---- per-thread weight fragment (round-14 verbatim, k = global channel) ----
__device__ __forceinline__ void load_w3(const float* __restrict__ W, int c,
                                        int k, int u, float4 w[3]) {
    const float* p = W + (size_t)k * 768 + c * 96 + u * 12;
    w[0] = *reinterpret_cast<const float4*>(p);
    w[1] = *reinterpret_cast<const float4*>(p + 4);
    w[2] = *reinterpret_cast<const float4*>(p + 8);
}

// One 32-d chunk of bilinear accumulation (round-14 verbatim, bit-exact).
template<int J>
__device__ __forceinline__ void bilin_chunk_reg(const float4 w[3], int c,
                                                const float* xbase, int u,
                                                float acc[][3]) {
    const float wf[12] = { w[0].x, w[0].y, w[0].z, w[0].w,
                           w[1].x, w[1].y, w[1].z, w[1].w,
                           w[2].x, w[2].y, w[2].z, w[2].w };
    const int inner = ((c & 3) << 5) + (u << 2);
    const int half = c >> 2;
#pragma unroll
    for (int j = 0; j < J; ++j) {
        float4 xv = *reinterpret_cast<const float4*>(
            xbase + (2 * j + half) * 128 + inner);
        const float xf[4] = { xv.x, xv.y, xv.z, xv.w };
#pragma unroll
        for (int dl = 0; dl < 4; ++dl)
#pragma unroll
            for (int v = 0; v < 3; ++v)
                acc[j][v] += wf[dl * 3 + v] * xf[dl];
    }
}

// Reduce the 8 u-partials (pairwise tree, round-14 order) for this k-slice
// and write the R x 32 result rows into a GLOBAL full-width buffer.
template<int R>
__device__ __forceinline__ void reduce_to_global(const float* part,
                                                 const float* __restrict__ bias,
                                                 float aval, float* gdst,
                                                 int ks, int t) {
    if (t < R * 32) {
        int r = t >> 5, c2 = t & 31;
        float p0 = part[(0 * R + r) * PS + c2];
        float p1 = part[(1 * R + r) * PS + c2];
        float p2 = part[(2 * R + r) * PS + c2];
        float p3 = part[(3 * R + r) * PS + c2];
        float p4 = part[(4 * R + r) * PS + c2];
        float p5 = part[(5 * R + r) * PS + c2];
        float p6 = part[(6 * R + r) * PS + c2];
        float p7 = part[(7 * R + r) * PS + c2];
        float s = ((p0 + p1) + (p2 + p3)) + ((p4 + p5) + (p6 + p7));
        gdst[r * 128 + ks + c2] = prelu(s + bias[ks + c2], aval);
    }
}

// Intra-group (4 blocks, same XCD) barrier: release data, arrive, spin.
__device__ __forceinline__ void group_barrier(int* ctr, int t) {
    __threadfence();                 // release this thread's global writes
    __syncthreads();                 // all block threads' writes ordered
    if (t == 0) {
        __hip_atomic_fetch_add(ctr, 1, __ATOMIC_RELEASE,
                               __HIP_MEMORY_SCOPE_AGENT);
        while (__hip_atomic_load(ctr, __ATOMIC_ACQUIRE,
                                 __HIP_MEMORY_SCOPE_AGENT) < 4) { }
    }
    __syncthreads();                 // broadcast arrival to all waves
}

// 32 blocks = 8 batches x 4 k-slices. 256 threads = 32 k' x 8 u.
__global__ __launch_bounds__(256, 1) void encoder_fused(
    const float* __restrict__ points,
    const float* __restrict__ vec2, const float* __restrict__ vec1,
    const float* __restrict__ vec0,
    const float* __restrict__ Wp,  const float* __restrict__ bp,
    const float* __restrict__ aL,
    const float* __restrict__ Wb2, const float* __restrict__ bb2,
    const float* __restrict__ a2,
    const float* __restrict__ Wb1, const float* __restrict__ bb1,
    const float* __restrict__ Ws1, const float* __restrict__ bs1,
    const float* __restrict__ a1,
    const float* __restrict__ Wb0, const float* __restrict__ bb0,
    const float* __restrict__ Ws0, const float* __restrict__ bs0,
    const float* __restrict__ a0,
    const int* __restrict__ cl2, const int* __restrict__ cr2,
    const int* __restrict__ cl1, const int* __restrict__ cr1,
    const int* __restrict__ cs1,
    const int* __restrict__ cl0, const int* __restrict__ cr0,
    const int* __restrict__ cs0,
    int* __restrict__ ctrs,        // [8][4] zeroed by memset node each call
    float* __restrict__ gbuf,      // gh2[8][5][128] gt1[8][2][128] gh1[8][2][128] gh0[8][128]
    float* __restrict__ out,
    int N3, int N2, int N1)
{
    __shared__ float leaf[12][DIM];
    __shared__ float h2s[5][DIM];
    __shared__ float t1s[2][DIM];
    __shared__ float h1s[2][DIM];
    __shared__ float h0s[DIM];
    __shared__ float part[8 * 5 * PS];
    __shared__ int   ljs[12];

    const int b  = blockIdx.x & 7;        // batch  (partners share XCD)
    const int ks = (blockIdx.x >> 3) * 32; // k-slice base
    const int t = threadIdx.x;            // 0..255
    const int k  = ks + (t >> 3);         // global output channel
    const int u  = t & 7;
    const int kk = t & 127;

    float* gh2 = gbuf + (size_t)b * 640;
    float* gt1 = gbuf + 5120 + (size_t)b * 256;
    float* gh1 = gbuf + 7168 + (size_t)b * 256;
    float* gh0 = gbuf + 9216 + (size_t)b * 128;
    int* ctr = ctrs + b * 4;

    // ---- uniform index chain ----
    const int m0 = cl0[0], m1 = cr0[0];
    int nj[5];
    nj[0] = cl1[m0]; nj[1] = cr1[m0];
    nj[2] = cl1[m1]; nj[3] = cr1[m1];
    nj[4] = cs0[0];
    if (t == 0) {
        ljs[0] = cl2[nj[0]]; ljs[1] = cr2[nj[0]];
        ljs[2] = cl2[nj[1]]; ljs[3] = cr2[nj[1]];
        ljs[4] = cl2[nj[2]]; ljs[5] = cr2[nj[2]];
        ljs[6] = cl2[nj[3]]; ljs[7] = cr2[nj[3]];
        ljs[8] = cl2[nj[4]]; ljs[9] = cr2[nj[4]];
        ljs[10] = cs1[m0];   ljs[11] = cs1[m1];
    }

    // ---- preloads ----
    const float aLv = aL[0], a2v = a2[0], a1v = a1[0], a0v = a0[0];
    const float wp0 = Wp[kk * 3 + 0], wp1 = Wp[kk * 3 + 1], wp2 = Wp[kk * 3 + 2];
    const float bpv = bp[kk];
    float v2r[5][3], v1r[2][3], v0r[3];
#pragma unroll
    for (int j = 0; j < 5; ++j) {
        size_t vb = ((size_t)b * N2 + nj[j]) * 3;
        v2r[j][0] = vec2[vb]; v2r[j][1] = vec2[vb + 1]; v2r[j][2] = vec2[vb + 2];
    }
    {
        size_t vb0 = ((size_t)b * N1 + m0) * 3, vb1 = ((size_t)b * N1 + m1) * 3;
        v1r[0][0] = vec1[vb0]; v1r[0][1] = vec1[vb0 + 1]; v1r[0][2] = vec1[vb0 + 2];
        v1r[1][0] = vec1[vb1]; v1r[1][1] = vec1[vb1 + 1]; v1r[1][2] = vec1[vb1 + 2];
    }
    v0r[0] = vec0[b * 3]; v0r[1] = vec0[b * 3 + 1]; v0r[2] = vec0[b * 3 + 2];

    // ---- depth-3 weight pipeline (round-14 verbatim; k-sliced rows) ----
    float4 w[4][3];
    load_w3(Wb2, 0, k, u, w[0]);
    load_w3(Wb2, 1, k, u, w[1]);
    load_w3(Wb2, 2, k, u, w[2]);

    __syncthreads();                      // ljs visible

    // ---- leaf rows (full width; redundant per slice — cheap) ----
    for (int idx = t; idx < 12 * DIM; idx += 256) {
        int r = idx >> 7;
        size_t pb = ((size_t)b * N3 + ljs[r]) * 3;
        float p0 = points[pb], p1 = points[pb + 1], p2 = points[pb + 2];
        leaf[r][idx & 127] = prelu(p0 * wp0 + p1 * wp1 + p2 * wp2 + bpv, aLv);
    }
    __syncthreads();                      // leaf visible

    // ================ layer 2: 5 nodes, 32 k-channels ======================
    float acc2[5][3] = {};
#pragma unroll
    for (int c = 0; c < 8; ++c) {
        if (c < 5) load_w3(Wb2, c + 3, k, u, w[(c + 3) & 3]);
        else       load_w3(Wb1, c - 5, k, u, w[(c + 3) & 3]);
        bilin_chunk_reg<5>(w[c & 3], c, &leaf[0][0], u, acc2);
    }
#pragma unroll
    for (int j = 0; j < 5; ++j) {
        float z = v2r[j][0] * acc2[j][0] + v2r[j][1] * acc2[j][1] +
                  v2r[j][2] * acc2[j][2];
        part[(u * 5 + j) * PS + (t >> 3)] = z;
    }
    __syncthreads();
    reduce_to_global<5>(part, bb2, a2v, gh2, ks, t);
    group_barrier(ctr + 0, t);            // exchange h2 slices
    for (int idx = t; idx < 640; idx += 256)
        (&h2s[0][0])[idx] = gh2[idx];
    __syncthreads();

    // ================ layer 1 bilinear: 2 nodes ============================
    float acc1[2][3] = {};
#pragma unroll
    for (int c = 0; c < 8; ++c) {
        if (c < 5) load_w3(Wb1, c + 3, k, u, w[(c + 3) & 3]);
        else       load_w3(Wb0, c - 5, k, u, w[(c + 3) & 3]);
        bilin_chunk_reg<2>(w[c & 3], c, &h2s[0][0], u, acc1);
    }
#pragma unroll
    for (int n = 0; n < 2; ++n) {
        float z = v1r[n][0] * acc1[n][0] + v1r[n][1] * acc1[n][1] +
                  v1r[n][2] * acc1[n][2];
        part[(u * 2 + n) * PS + (t >> 3)] = z;
    }
    __syncthreads();
    reduce_to_global<2>(part, bb1, a1v, gt1, ks, t);
    group_barrier(ctr + 1, t);            // exchange t1 slices
    for (int idx = t; idx < 256; idx += 256)
        (&t1s[0][0])[idx] = gt1[idx];
    __syncthreads();

    // ---- layer 1 sampled linear (k-sliced rows of Ws1) ----
    {
        float4 wv[8];
#pragma unroll
        for (int i = 0; i < 8; ++i)
            wv[i] = *reinterpret_cast<const float4*>(
                Ws1 + (size_t)k * 256 + ((i * 8 + u) << 2));
#pragma unroll
        for (int n = 0; n < 2; ++n) {
            const float* x0 = n ? &t1s[1][0] : &t1s[0][0];
            const float* x1 = n ? &leaf[11][0] : &leaf[10][0];
            float acc = 0.f;
#pragma unroll
            for (int i = 0; i < 8; ++i) {
                const float* xr = (i < 4) ? (x0 + (i << 5) + (u << 2))
                                          : (x1 + ((i - 4) << 5) + (u << 2));
                float4 xv = *reinterpret_cast<const float4*>(xr);
                acc += wv[i].x * xv.x + wv[i].y * xv.y +
                       wv[i].z * xv.z + wv[i].w * xv.w;
            }
            part[(u * 2 + n) * PS + (t >> 3)] = acc;
        }
    }
    __syncthreads();
    reduce_to_global<2>(part, bs1, a1v, gh1, ks, t);
    group_barrier(ctr + 2, t);            // exchange h1 slices
    for (int idx = t; idx < 256; idx += 256)
        (&h1s[0][0])[idx] = gh1[idx];
    __syncthreads();

    // ================ root bilinear: 1 node ================================
    float acc0[1][3] = {};
#pragma unroll
    for (int c = 0; c < 8; ++c) {
        if (c < 5) load_w3(Wb0, c + 3, k, u, w[(c + 3) & 3]);
        bilin_chunk_reg<1>(w[c & 3], c, &h1s[0][0], u, acc0);
    }
    {
        float z = v0r[0] * acc0[0][0] + v0r[1] * acc0[0][1] + v0r[2] * acc0[0][2];
        part[u * PS + (t >> 3)] = z;
    }
    __syncthreads();
    reduce_to_global<1>(part, bb0, a0v, gh0, ks, t);
    group_barrier(ctr + 3, t);            // exchange h0 slices
    for (int idx = t; idx < 128; idx += 256)
        h0s[idx] = gh0[idx];
    __syncthreads();

    // ---- root sampled linear -> output slice ----
    {
        float4 wv[8];
#pragma unroll
        for (int i = 0; i < 8; ++i)
            wv[i] = *reinterpret_cast<const float4*>(
                Ws0 + (size_t)k * 256 + ((i * 8 + u) << 2));
        float acc = 0.f;
#pragma unroll
        for (int i = 0; i < 8; ++i) {
            const float* xr = (i < 4) ? (&h0s[0] + (i << 5) + (u << 2))
                                      : (&h2s[4][0] + ((i - 4) << 5) + (u << 2));
            float4 xv = *reinterpret_cast<const float4*>(xr);
            acc += wv[i].x * xv.x + wv[i].y * xv.y +
                   wv[i].z * xv.z + wv[i].w * xv.w;
        }
        part[u * PS + (t >> 3)] = acc;
    }
    __syncthreads();
    if (t < 32) {
        float p0 = part[0 * PS + t], p1 = part[1 * PS + t];
        float p2 = part[2 * PS + t], p3 = part[3 * PS + t];
        float p4 = part[4 * PS + t], p5 = part[5 * PS + t];
        float p6 = part[6 * PS + t], p7 = part[7 * PS + t];
        float s = ((p0 + p1) + (p2 + p3)) + ((p4 + p5) + (p6 + p7));
        out[(size_t)b * DIM + ks + t] = prelu(s + bs0[ks + t], a0v);
    }
}

// ---------------- launch ---------------------------------------------------
extern "C" void kernel_launch(void* const* d_in, const int* in_sizes, int n_in,
                              void* d_out, int out_size, void* d_ws, size_t ws_size,
                              hipStream_t stream)
{
    const float* points = (const float*)d_in[0];
    const float* vec2   = (const float*)d_in[1];
    const float* vec1   = (const float*)d_in[2];
    const float* vec0   = (const float*)d_in[3];
    const float* Wp     = (const float*)d_in[4];
    const float* bp     = (const float*)d_in[5];
    const float* a_leaf = (const float*)d_in[6];
    const float* Wb2    = (const float*)d_in[7];
    const float* bb2    = (const float*)d_in[8];
    const float* a2     = (const float*)d_in[9];
    const float* Wb1    = (const float*)d_in[10];
    const float* bb1    = (const float*)d_in[11];
    const float* Ws1    = (const float*)d_in[12];
    const float* bs1    = (const float*)d_in[13];
    const float* a1     = (const float*)d_in[14];
    const float* Wb0    = (const float*)d_in[15];
    const float* bb0    = (const float*)d_in[16];
    const float* Ws0    = (const float*)d_in[17];
    const float* bs0    = (const float*)d_in[18];
    const float* a0     = (const float*)d_in[19];
    const int* cl2 = (const int*)d_in[20];
    const int* cr2 = (const int*)d_in[21];
    const int* cl1 = (const int*)d_in[22];
    const int* cr1 = (const int*)d_in[23];
    const int* cs1 = (const int*)d_in[24];
    const int* cl0 = (const int*)d_in[25];
    const int* cr0 = (const int*)d_in[26];
    const int* cs0 = (const int*)d_in[27];

    const int B = 8, N3 = 131072, N2 = 65536, N1 = 1024;
    (void)in_sizes; (void)n_in; (void)out_size; (void)ws_size;

    int*   ctrs = (int*)d_ws;                      // [8][4] sync counters
    float* gbuf = (float*)d_ws + 64;               // exchange slices (~41KB)

    // zero the sync counters every call (replay-safe graph memset node)
    hipMemsetAsync(d_ws, 0, 256, stream);

    encoder_fused<<<32, 256, 0, stream>>>(
        points, vec2, vec1, vec0,
        Wp, bp, a_leaf,
        Wb2, bb2, a2,
        Wb1, bb1, Ws1, bs1, a1,
        Wb0, bb0, Ws0, bs0, a0,
        cl2, cr2, cl1, cr1, cs1, cl0, cr0, cs0,
        ctrs, gbuf, (float*)d_out, N3, N2, N1);
}